// Round 12
// baseline (2759.821 us; speedup 1.0000x reference)
//
#include <hip/hip_runtime.h>
#include <hip/hip_bf16.h>
#include <cstddef>

#define NB 32      // batch
#define NP 196     // pixels
#define NE 2048    // encoder dim
#define ND 512     // decoder/att/emb dim
#define NV 32000   // vocab
#define NL 21
#define NT 20      // decode steps

typedef __attribute__((ext_vector_type(8))) short short8;   // 8 bf16 (4 VGPRs)
typedef __attribute__((ext_vector_type(4))) float f32x4;

__device__ __forceinline__ unsigned short f2b(float f) {
    __hip_bfloat16 h = __float2bfloat16(f);      // RNE
    return *reinterpret_cast<unsigned short*>(&h);
}
__device__ __forceinline__ float b2f_lo(unsigned int u) {
    union { unsigned int i; float f; } v; v.i = u << 16; return v.f;
}
__device__ __forceinline__ float b2f_hi(unsigned int u) {
    union { unsigned int i; float f; } v; v.i = u & 0xffff0000u; return v.f;
}

// ---------------- setup ----------------

__global__ void k_sort(const int* __restrict__ lens, int* __restrict__ sind, int* __restrict__ dlens,
                       int* __restrict__ rowmap, int* __restrict__ mpad)
{
    int i = threadIdx.x;
    if (i < NB) {
        int li = lens[i];
        int r = 0;
        for (int j = 0; j < NB; ++j) {
            int lj = lens[j];
            if (lj > li || (lj == li && j < i)) ++r;
        }
        sind[r] = i;
        dlens[r] = li - 1;
    }
    __syncthreads();
    if (i == 0) {
        int c = 0;
        for (int t = 0; t < NT; ++t)
            for (int b = 0; b < NB; ++b)
                if (t < dlens[b]) rowmap[c++] = t * NB + b;
        int pad = (c + 63) & ~63;
        for (int r = c; r < pad; ++r) rowmap[r] = -1;
        mpad[0] = pad;
    }
}

__global__ __launch_bounds__(256) void k_mean(const float* __restrict__ enc, const int* __restrict__ sind,
                                              float* __restrict__ mean_enc)
{
    int b = blockIdx.y;
    int k = blockIdx.x * 256 + threadIdx.x;
    const float* e = enc + (size_t)sind[b] * NP * NE + k;
    float s0 = 0.f, s1 = 0.f, s2 = 0.f, s3 = 0.f;
    for (int p = 0; p < NP; p += 4) {
        s0 += e[(size_t)(p + 0) * NE];
        s1 += e[(size_t)(p + 1) * NE];
        s2 += e[(size_t)(p + 2) * NE];
        s3 += e[(size_t)(p + 3) * NE];
    }
    mean_enc[(size_t)b * NE + k] = (s0 + s1 + s2 + s3) * (1.0f / NP);
}

__global__ __launch_bounds__(256) void k_zero(const int* __restrict__ dlens, float* __restrict__ out)
{
    int b = blockIdx.x / NT, t = blockIdx.x % NT;
    if (t < dlens[b]) return;
    float4 z = {0.f, 0.f, 0.f, 0.f};
    float4* row = (float4*)(out + ((size_t)b * NT + t) * NV);
    for (int i = threadIdx.x; i < NV / 4; i += 256) row[i] = z;
}

// ---------------- h0/c0 skinny GEMM, split-K=8 (grid 16 x 8) -> partials in spart ----------------
__global__ __launch_bounds__(256) void gemm_skinny_split(
    const float* __restrict__ A0, const float* __restrict__ W0a, const float* __restrict__ W0b,
    float* __restrict__ spart)
{
    __shared__ float As[32][32];
    __shared__ float Ws[64][33];
    int n0 = blockIdx.x * 64;
    int ks = blockIdx.y;
    int tid = threadIdx.x;
    int lb = tid / 8, lkq = tid % 8;
    int b4 = (tid / 32) * 4, nl = (tid % 32) * 2;
    float acc[4][2] = {};
    for (int kt = ks * 256; kt < ks * 256 + 256; kt += 32) {
        float4 a4 = *reinterpret_cast<const float4*>(A0 + (size_t)lb * NE + kt + lkq * 4);
        As[lkq * 4 + 0][lb] = a4.x; As[lkq * 4 + 1][lb] = a4.y;
        As[lkq * 4 + 2][lb] = a4.z; As[lkq * 4 + 3][lb] = a4.w;
        #pragma unroll
        for (int r = 0; r < 2; ++r) {
            int s = tid + r * 256;
            int n_l = s / 8, kq = s % 8;
            int ng = n0 + n_l;
            const float* wrow = (ng < 512) ? (W0a + (size_t)ng * NE)
                                           : (W0b + (size_t)(ng - 512) * NE);
            float4 w4 = *reinterpret_cast<const float4*>(wrow + kt + kq * 4);
            Ws[n_l][kq * 4 + 0] = w4.x; Ws[n_l][kq * 4 + 1] = w4.y;
            Ws[n_l][kq * 4 + 2] = w4.z; Ws[n_l][kq * 4 + 3] = w4.w;
        }
        __syncthreads();
        #pragma unroll
        for (int k = 0; k < 32; ++k) {
            float4 av = *reinterpret_cast<const float4*>(&As[k][b4]);
            float w0 = Ws[nl][k], w1 = Ws[nl + 1][k];
            acc[0][0] += av.x * w0; acc[0][1] += av.x * w1;
            acc[1][0] += av.y * w0; acc[1][1] += av.y * w1;
            acc[2][0] += av.z * w0; acc[2][1] += av.z * w1;
            acc[3][0] += av.w * w0; acc[3][1] += av.w * w1;
        }
        __syncthreads();
    }
    float* Cp = spart + (size_t)ks * NB * 1024;
    #pragma unroll
    for (int j = 0; j < 2; ++j)
        #pragma unroll
        for (int i = 0; i < 4; ++i)
            Cp[(size_t)(b4 + i) * 1024 + n0 + nl + j] = acc[i][j];
}

// combine partials + bias -> hcbuf[parity 0]; seed xh h-part (grid NB)
__global__ __launch_bounds__(256) void k_hc0(
    const float* __restrict__ spart, const float* __restrict__ ba, const float* __restrict__ bb,
    float* __restrict__ hc, float* __restrict__ xh)
{
    int b = blockIdx.x;
    for (int ng = threadIdx.x; ng < 1024; ng += 256) {
        float s = (ng < 512) ? ba[ng] : bb[ng - 512];
        #pragma unroll
        for (int ks = 0; ks < 8; ++ks)
            s += spart[(size_t)ks * NB * 1024 + (size_t)b * 1024 + ng];
        hc[(size_t)b * 1024 + ng] = s;
        if (ng < 512) xh[(size_t)b * 3072 + 2560 + ng] = s;
    }
}

// ---------------- att1 GEMM (bf16 MFMA), XCD-swizzled ----------------
__global__ __launch_bounds__(256) void gemm_att1_mfma(
    const float* __restrict__ enc, const float* __restrict__ W_ea,
    const float* __restrict__ bias, unsigned short* __restrict__ att1B,
    const int* __restrict__ sind)
{
    int fid = blockIdx.x;
    int c = fid & 7, x = (fid >> 3) & 7, pg = fid >> 6;
    int p = pg * 8 + c;
    if (p >= 98) return;
    int bm0 = p * 64, bn0 = x * 64;
    __shared__ unsigned short As[64][40];
    __shared__ unsigned short Bs[64][40];
    int tid = threadIdx.x;
    int w = tid >> 6, lane = tid & 63;
    int srow = tid >> 2, schunk = (tid & 3) * 8;
    int mg = bm0 + srow;
    int bidx = mg / NP, pp = mg - bidx * NP;
    const float* arow = enc + ((size_t)sind[bidx] * NP + pp) * NE + schunk;
    const float* brow = W_ea + (size_t)(bn0 + srow) * NE + schunk;
    int frow = lane & 15, fk = (lane >> 4) * 8;
    f32x4 acc[4] = {};
    for (int kt = 0; kt < NE; kt += 32) {
        float4 a0 = *reinterpret_cast<const float4*>(arow + kt);
        float4 a1 = *reinterpret_cast<const float4*>(arow + kt + 4);
        float4 b0 = *reinterpret_cast<const float4*>(brow + kt);
        float4 b1 = *reinterpret_cast<const float4*>(brow + kt + 4);
        uint4 av, bv;
        av.x = f2b(a0.x) | ((unsigned)f2b(a0.y) << 16);
        av.y = f2b(a0.z) | ((unsigned)f2b(a0.w) << 16);
        av.z = f2b(a1.x) | ((unsigned)f2b(a1.y) << 16);
        av.w = f2b(a1.z) | ((unsigned)f2b(a1.w) << 16);
        bv.x = f2b(b0.x) | ((unsigned)f2b(b0.y) << 16);
        bv.y = f2b(b0.z) | ((unsigned)f2b(b0.w) << 16);
        bv.z = f2b(b1.x) | ((unsigned)f2b(b1.y) << 16);
        bv.w = f2b(b1.z) | ((unsigned)f2b(b1.w) << 16);
        *reinterpret_cast<uint4*>(&As[srow][schunk]) = av;
        *reinterpret_cast<uint4*>(&Bs[srow][schunk]) = bv;
        __syncthreads();
        short8 af = *reinterpret_cast<const short8*>(&As[w * 16 + frow][fk]);
        #pragma unroll
        for (int n = 0; n < 4; ++n) {
            short8 bf = *reinterpret_cast<const short8*>(&Bs[n * 16 + frow][fk]);
            acc[n] = __builtin_amdgcn_mfma_f32_16x16x32_bf16(af, bf, acc[n], 0, 0, 0);
        }
        __syncthreads();
    }
    int crow = bm0 + w * 16 + (lane >> 4) * 4;
    int ccol0 = lane & 15;
    #pragma unroll
    for (int n = 0; n < 4; ++n) {
        int col = bn0 + n * 16 + ccol0;
        float bb2 = bias[col];
        #pragma unroll
        for (int i = 0; i < 4; ++i)
            att1B[(size_t)(crow + i) * ND + col] = f2b(acc[n][i] + bb2);
    }
}

// ---------------- preds GEMM (bf16 MFMA), XCD-swizzled ----------------
__global__ __launch_bounds__(256) void gemm_preds_mfma(
    const unsigned short* __restrict__ hseqB, const float* __restrict__ W_fc,
    const float* __restrict__ bias, float* __restrict__ out,
    const int* __restrict__ rowmap, const int* __restrict__ mpad)
{
    int fid = blockIdx.x;
    int c = fid & 7;
    int rem = fid >> 3;
    int m = rem % 10, g = rem / 10;
    int n = g * 8 + c;
    if (n >= 250) return;
    int bm0 = m * 64;
    if (bm0 >= mpad[0]) return;
    int bn0 = n * 128;
    __shared__ unsigned short As[64][40];
    __shared__ unsigned short Bs[128][40];
    int tid = threadIdx.x;
    int w = tid >> 6, lane = tid & 63;
    int srow = tid >> 2, schunk = (tid & 3) * 8;
    int rid = rowmap[bm0 + srow];
    const unsigned short* aptr = hseqB + (size_t)(rid < 0 ? 0 : rid) * ND + schunk;
    const float* bptr0 = W_fc + (size_t)(bn0 + srow) * ND + schunk;
    const float* bptr1 = W_fc + (size_t)(bn0 + 64 + srow) * ND + schunk;
    int frow = lane & 15, fk = (lane >> 4) * 8;
    f32x4 acc[8] = {};
    for (int kt = 0; kt < ND; kt += 32) {
        uint4 av = *reinterpret_cast<const uint4*>(aptr + kt);
        float4 c0 = *reinterpret_cast<const float4*>(bptr0 + kt);
        float4 c1 = *reinterpret_cast<const float4*>(bptr0 + kt + 4);
        float4 d0 = *reinterpret_cast<const float4*>(bptr1 + kt);
        float4 d1 = *reinterpret_cast<const float4*>(bptr1 + kt + 4);
        uint4 bv0, bv1;
        bv0.x = f2b(c0.x) | ((unsigned)f2b(c0.y) << 16);
        bv0.y = f2b(c0.z) | ((unsigned)f2b(c0.w) << 16);
        bv0.z = f2b(c1.x) | ((unsigned)f2b(c1.y) << 16);
        bv0.w = f2b(c1.z) | ((unsigned)f2b(c1.w) << 16);
        bv1.x = f2b(d0.x) | ((unsigned)f2b(d0.y) << 16);
        bv1.y = f2b(d0.z) | ((unsigned)f2b(d0.w) << 16);
        bv1.z = f2b(d1.x) | ((unsigned)f2b(d1.y) << 16);
        bv1.w = f2b(d1.z) | ((unsigned)f2b(d1.w) << 16);
        *reinterpret_cast<uint4*>(&As[srow][schunk]) = av;
        *reinterpret_cast<uint4*>(&Bs[srow][schunk]) = bv0;
        *reinterpret_cast<uint4*>(&Bs[64 + srow][schunk]) = bv1;
        __syncthreads();
        short8 af = *reinterpret_cast<const short8*>(&As[w * 16 + frow][fk]);
        #pragma unroll
        for (int nn = 0; nn < 8; ++nn) {
            short8 bf = *reinterpret_cast<const short8*>(&Bs[nn * 16 + frow][fk]);
            acc[nn] = __builtin_amdgcn_mfma_f32_16x16x32_bf16(af, bf, acc[nn], 0, 0, 0);
        }
        __syncthreads();
    }
    int rl0 = w * 16 + (lane >> 4) * 4;
    int ccol0 = lane & 15;
    #pragma unroll
    for (int i = 0; i < 4; ++i) {
        int rm = rowmap[bm0 + rl0 + i];
        if (rm < 0) continue;
        int t = rm / NB, b = rm % NB;
        float* orow = out + ((size_t)b * NT + t) * NV;
        #pragma unroll
        for (int nn = 0; nn < 8; ++nn) {
            int col = bn0 + nn * 16 + ccol0;
            orow[col] = acc[nn][i] + bias[col];
        }
    }
}

// ---------------- k_attgcell: cell(t-1) from reduced gates + attg GEMM (40 blocks) ----------------
// All blocks redundantly run the cell into LDS hBT (bf16, transposed [d][b]); block 0 commits
// hcbuf[t&1] (read parity (t-1)&1 differs -> no race), hseqB[t-1], xh h-part.
__global__ __launch_bounds__(256) void k_attgcell(
    const float* __restrict__ gates, const int* __restrict__ dlens,
    const float* __restrict__ W_da, const float* __restrict__ W_fb,
    const float* __restrict__ b_da, const float* __restrict__ b_fb,
    float* __restrict__ hcbuf, float* __restrict__ attg,
    unsigned short* __restrict__ hseqB, float* __restrict__ xh, int t)
{
    __shared__ unsigned short hBT[512][36];   // [d][b], 72B rows
    __shared__ float Ws[64][33];
    int tid = threadIdx.x;
    const float* hcR = hcbuf + (size_t)((t > 0 ? (t - 1) : 0) & 1) * NB * 1024;
    if (t == 0) {
        for (int i = 0; i < 64; ++i) {
            int idx = i * 256 + tid, b = idx >> 9, d = idx & 511;
            hBT[d][b] = f2b(hcR[(size_t)b * 1024 + d]);
        }
    } else {
        float* hcW = hcbuf + (size_t)(t & 1) * NB * 1024;
        bool blk0 = (blockIdx.x == 0);
        for (int i = 0; i < 64; ++i) {
            int idx = i * 256 + tid, b = idx >> 9, d = idx & 511;
            const float* gb = gates + (size_t)b * 2048;
            float g0 = gb[d], g1 = gb[512 + d], g2 = gb[1024 + d], g3 = gb[1536 + d];
            float ig = 1.f / (1.f + expf(-g0));
            float fg = 1.f / (1.f + expf(-g1));
            float gt = tanhf(g2);
            float og = 1.f / (1.f + expf(-g3));
            float h_old = hcR[(size_t)b * 1024 + d];
            float c_old = hcR[(size_t)b * 1024 + 512 + d];
            float c_new = fg * c_old + ig * gt;
            float h_new = og * tanhf(c_new);
            bool live = (t - 1) < dlens[b];
            float hv = live ? h_new : h_old;
            float cv = live ? c_new : c_old;
            hBT[d][b] = f2b(hv);
            if (blk0) {
                hcW[(size_t)b * 1024 + d] = hv;
                hcW[(size_t)b * 1024 + 512 + d] = cv;
                hseqB[((size_t)(t - 1) * NB + b) * ND + d] = f2b(h_new);
                xh[(size_t)b * 3072 + 2560 + d] = hv;
            }
        }
    }
    __syncthreads();

    int n0 = blockIdx.x * 64;
    int b4 = (tid / 32) * 4, nl = (tid % 32) * 2;
    float acc[4][2] = {};
    for (int kt = 0; kt < 512; kt += 32) {
        #pragma unroll
        for (int r = 0; r < 2; ++r) {
            int s = tid + r * 256;
            int n_l = s / 8, kq = s % 8;
            int ng = n0 + n_l;
            const float* wrow = (ng < 512) ? (W_da + (size_t)ng * 512)
                                           : (W_fb + (size_t)(ng - 512) * 512);
            float4 w4 = *reinterpret_cast<const float4*>(wrow + kt + kq * 4);
            Ws[n_l][kq * 4 + 0] = w4.x; Ws[n_l][kq * 4 + 1] = w4.y;
            Ws[n_l][kq * 4 + 2] = w4.z; Ws[n_l][kq * 4 + 3] = w4.w;
        }
        __syncthreads();
        #pragma unroll
        for (int k = 0; k < 32; ++k) {
            uint2 u = *reinterpret_cast<const uint2*>(&hBT[kt + k][b4]);
            float a0 = b2f_lo(u.x), a1 = b2f_hi(u.x);
            float a2 = b2f_lo(u.y), a3 = b2f_hi(u.y);
            float w0 = Ws[nl][k], w1 = Ws[nl + 1][k];
            acc[0][0] += a0 * w0; acc[0][1] += a0 * w1;
            acc[1][0] += a1 * w0; acc[1][1] += a1 * w1;
            acc[2][0] += a2 * w0; acc[2][1] += a2 * w1;
            acc[3][0] += a3 * w0; acc[3][1] += a3 * w1;
        }
        __syncthreads();
    }
    #pragma unroll
    for (int j = 0; j < 2; ++j) {
        int ng = n0 + nl + j;
        float bias = (ng < 512) ? b_da[ng] : b_fb[ng - 512];
        #pragma unroll
        for (int i = 0; i < 4; ++i)
            attg[(size_t)(b4 + i) * 2560 + ng] = acc[i][j] + bias;
    }
}

// ---------------- k_att: e (thread-per-p, redundant x8) + softmax + awe + gate + xh
//                  + gates bias-init (grid 8 x 32) ----------------
__global__ __launch_bounds__(256) void k_att(
    const float* __restrict__ enc, const int* __restrict__ sind, const int* __restrict__ dlens,
    const int* __restrict__ caps, const float* __restrict__ emb_W,
    const unsigned short* __restrict__ att1B, const float* __restrict__ attg,
    const float* __restrict__ w_fa, const float* __restrict__ b_fa,
    const float* __restrict__ b_ih, const float* __restrict__ b_hh,
    float* __restrict__ xh, float* __restrict__ gates,
    float* __restrict__ out_alpha, int t)
{
    __shared__ float att2s[512];
    __shared__ float wfas[512];
    __shared__ float es[256];
    __shared__ float red[256];
    int kc = blockIdx.x, b = blockIdx.y, tid = threadIdx.x;
    const float* ag = attg + (size_t)b * 2560;
    att2s[tid] = ag[tid]; att2s[256 + tid] = ag[256 + tid];
    wfas[tid] = w_fa[tid]; wfas[256 + tid] = w_fa[256 + tid];
    __syncthreads();
    // e score: one thread per p, 512-dim dot on bf16 att1 row
    float ev = -1e30f;
    if (tid < NP) {
        const unsigned short* row = att1B + ((size_t)b * NP + tid) * ND;
        float s0 = 0.f, s1 = 0.f;
        #pragma unroll 8
        for (int d = 0; d < 512; d += 8) {
            uint4 u = *reinterpret_cast<const uint4*>(row + d);
            s0 += fmaxf(b2f_lo(u.x) + att2s[d + 0], 0.f) * wfas[d + 0];
            s1 += fmaxf(b2f_hi(u.x) + att2s[d + 1], 0.f) * wfas[d + 1];
            s0 += fmaxf(b2f_lo(u.y) + att2s[d + 2], 0.f) * wfas[d + 2];
            s1 += fmaxf(b2f_hi(u.y) + att2s[d + 3], 0.f) * wfas[d + 3];
            s0 += fmaxf(b2f_lo(u.z) + att2s[d + 4], 0.f) * wfas[d + 4];
            s1 += fmaxf(b2f_hi(u.z) + att2s[d + 5], 0.f) * wfas[d + 5];
            s0 += fmaxf(b2f_lo(u.w) + att2s[d + 6], 0.f) * wfas[d + 6];
            s1 += fmaxf(b2f_hi(u.w) + att2s[d + 7], 0.f) * wfas[d + 7];
        }
        ev = s0 + s1 + b_fa[0];
    }
    red[tid] = ev; __syncthreads();
    for (int s2 = 128; s2 > 0; s2 >>= 1) { if (tid < s2) red[tid] = fmaxf(red[tid], red[tid + s2]); __syncthreads(); }
    float m = red[0]; __syncthreads();
    float xe = (tid < NP) ? expf(ev - m) : 0.f;
    red[tid] = xe; __syncthreads();
    for (int s2 = 128; s2 > 0; s2 >>= 1) { if (tid < s2) red[tid] += red[tid + s2]; __syncthreads(); }
    float inv = 1.0f / red[0];
    __syncthreads();
    es[tid] = xe * inv;
    __syncthreads();

    // gates bias-init for this (b, kc) slice (consumed by k_gates atomicAdd)
    int n = kc * 256 + tid;
    gates[(size_t)b * 2048 + n] = b_ih[n] + b_hh[n];

    // awe + gate for this block's 256 k-columns
    int k = kc * 256 + tid;
    const float* ec = enc + (size_t)sind[b] * NP * NE + k;
    float s0 = 0.f, s1 = 0.f, s2v = 0.f, s3 = 0.f;
    #pragma unroll 4
    for (int p = 0; p < NP; p += 4) {
        s0 += es[p + 0] * ec[(size_t)(p + 0) * NE];
        s1 += es[p + 1] * ec[(size_t)(p + 1) * NE];
        s2v += es[p + 2] * ec[(size_t)(p + 2) * NE];
        s3 += es[p + 3] * ec[(size_t)(p + 3) * NE];
    }
    float awe = (s0 + s1) + (s2v + s3);
    float gp = ag[512 + k];                     // includes b_fb
    float gate = 1.f / (1.f + expf(-gp));
    xh[(size_t)b * 3072 + 512 + k] = gate * awe;
    if (kc == 0) {
        bool live = (t < dlens[b]);
        if (tid < NP) out_alpha[((size_t)b * NT + t) * NP + tid] = live ? es[tid] : 0.f;
        const float* er = emb_W + (size_t)caps[sind[b] * NL + t] * ND;
        xh[(size_t)b * 3072 + tid] = er[tid];
        xh[(size_t)b * 3072 + 256 + tid] = er[256 + tid];
    }
}

// ---------------- k_gates: gates GEMM, atomicAdd into bias-initialized gates ----------------
__global__ __launch_bounds__(256) void k_gates(
    const float* __restrict__ xh, const float* __restrict__ W_ih, const float* __restrict__ W_hh,
    float* __restrict__ gates)
{
    __shared__ float smem[3200];
    int blk = blockIdx.x, tid = threadIdx.x;
    int nt = blk & 31, ks = blk >> 5;
    float* As = smem;
    float (*Ws)[33] = (float(*)[33])(smem + 1024);
    int n0 = nt * 64;
    int lb = tid / 8, lkq = tid % 8;
    int b4 = (tid / 32) * 4, nl = (tid % 32) * 2;
    float acc[4][2] = {};
    for (int kt = ks * 768; kt < ks * 768 + 768; kt += 32) {
        float4 a4 = *reinterpret_cast<const float4*>(xh + (size_t)lb * 3072 + kt + lkq * 4);
        As[(lkq * 4 + 0) * 32 + lb] = a4.x; As[(lkq * 4 + 1) * 32 + lb] = a4.y;
        As[(lkq * 4 + 2) * 32 + lb] = a4.z; As[(lkq * 4 + 3) * 32 + lb] = a4.w;
        #pragma unroll
        for (int r = 0; r < 2; ++r) {
            int s = tid + r * 256;
            int n_l = s / 8, kq = s % 8;
            int ng = n0 + n_l;
            int kk = kt + kq * 4;
            const float* wrow = (kk < 2560) ? (W_ih + (size_t)ng * 2560 + kk)
                                            : (W_hh + (size_t)ng * 512 + (kk - 2560));
            float4 w4 = *reinterpret_cast<const float4*>(wrow);
            Ws[n_l][kq * 4 + 0] = w4.x; Ws[n_l][kq * 4 + 1] = w4.y;
            Ws[n_l][kq * 4 + 2] = w4.z; Ws[n_l][kq * 4 + 3] = w4.w;
        }
        __syncthreads();
        #pragma unroll
        for (int k = 0; k < 32; ++k) {
            float4 av = *reinterpret_cast<const float4*>(&As[k * 32 + b4]);
            float w0 = Ws[nl][k], w1 = Ws[nl + 1][k];
            acc[0][0] += av.x * w0; acc[0][1] += av.x * w1;
            acc[1][0] += av.y * w0; acc[1][1] += av.y * w1;
            acc[2][0] += av.z * w0; acc[2][1] += av.z * w1;
            acc[3][0] += av.w * w0; acc[3][1] += av.w * w1;
        }
        __syncthreads();
    }
    #pragma unroll
    for (int j = 0; j < 2; ++j)
        #pragma unroll
        for (int i = 0; i < 4; ++i)
            atomicAdd(&gates[(size_t)(b4 + i) * 2048 + n0 + nl + j], acc[i][j]);
}

// ---------------- k_fin: final cell (gates already bias-included) -> hseqB[NT-1] ----------------
__global__ __launch_bounds__(256) void k_fin(
    const float* __restrict__ gates, const float* __restrict__ hcbuf,
    unsigned short* __restrict__ hseqB)
{
    int b = blockIdx.x;
    const float* hcR = hcbuf + (size_t)((NT - 1) & 1) * NB * 1024 + (size_t)b * 1024;
    const float* gb = gates + (size_t)b * 2048;
    for (int d = threadIdx.x; d < ND; d += 256) {
        float g0 = gb[d], g1 = gb[512 + d], g2 = gb[1024 + d], g3 = gb[1536 + d];
        float ig = 1.f / (1.f + expf(-g0));
        float fg = 1.f / (1.f + expf(-g1));
        float gt = tanhf(g2);
        float og = 1.f / (1.f + expf(-g3));
        float c_old = hcR[512 + d];
        float c_new = fg * c_old + ig * gt;
        float h_new = og * tanhf(c_new);
        hseqB[((size_t)(NT - 1) * NB + b) * ND + d] = f2b(h_new);
    }
}

// ---------------- launcher ----------------
extern "C" void kernel_launch(void* const* d_in, const int* in_sizes, int n_in,
                              void* d_out, int out_size, void* d_ws, size_t ws_size,
                              hipStream_t stream)
{
    const float* enc   = (const float*)d_in[0];
    const int*   caps  = (const int*)d_in[1];
    const int*   clens = (const int*)d_in[2];
    const float* emb_W = (const float*)d_in[3];
    const float* W_ea  = (const float*)d_in[4];
    const float* b_ea  = (const float*)d_in[5];
    const float* W_da  = (const float*)d_in[6];
    const float* b_da  = (const float*)d_in[7];
    const float* w_fa  = (const float*)d_in[8];
    const float* b_fa  = (const float*)d_in[9];
    const float* W_ih  = (const float*)d_in[10];
    const float* b_ih  = (const float*)d_in[11];
    const float* W_hh  = (const float*)d_in[12];
    const float* b_hh  = (const float*)d_in[13];
    const float* W_h0  = (const float*)d_in[14];
    const float* b_h0  = (const float*)d_in[15];
    const float* W_c0  = (const float*)d_in[16];
    const float* b_c0  = (const float*)d_in[17];
    const float* W_fb  = (const float*)d_in[18];
    const float* b_fb  = (const float*)d_in[19];
    const float* W_fc  = (const float*)d_in[20];
    const float* b_fc  = (const float*)d_in[21];

    float* out = (float*)d_out;
    float* out_alpha = out + (size_t)NB * NT * NV;

    int* iws    = (int*)d_ws;
    int* sind   = iws;
    int* dlens  = iws + 32;
    int* rowmap = iws + 64;
    int* mpad   = iws + 704;
    float* base = (float*)d_ws + 1024;
    float* mean_enc = base;                         // 65536
    float* hcbuf = mean_enc + NB * NE;              // 2*32*1024 = 65536 (double-buffered h|c)
    float* attg  = hcbuf + 2 * NB * 1024;           // 81920
    float* xh    = attg + NB * 2560;                // 98304
    float* gates = xh + NB * 3072;                  // 65536 used; 262144 reserved (spart at setup)
    unsigned short* att1B = (unsigned short*)(gates + 262144);          // 6272*512 bf16
    unsigned short* hseqB = att1B + (size_t)NB * NP * ND;               // 640*512 bf16

    k_sort<<<1, 64, 0, stream>>>(clens, sind, dlens, rowmap, mpad);
    k_zero<<<NB * NT, 256, 0, stream>>>(dlens, out);
    k_mean<<<dim3(NE / 256, NB), 256, 0, stream>>>(enc, sind, mean_enc);
    gemm_skinny_split<<<dim3(16, 8), 256, 0, stream>>>(mean_enc, W_h0, W_c0, gates);
    k_hc0<<<dim3(NB), 256, 0, stream>>>(gates, b_h0, b_c0, hcbuf, xh);
    gemm_att1_mfma<<<dim3(832), 256, 0, stream>>>(enc, W_ea, b_ea, att1B, sind);

    for (int t = 0; t < NT; ++t) {
        k_attgcell<<<dim3(40), 256, 0, stream>>>(gates, dlens, W_da, W_fb, b_da, b_fb,
                                                 hcbuf, attg, hseqB, xh, t);
        k_att<<<dim3(8, NB), 256, 0, stream>>>(enc, sind, dlens, caps, emb_W,
                                               att1B, attg, w_fa, b_fa, b_ih, b_hh,
                                               xh, gates, out_alpha, t);
        k_gates<<<dim3(128), 256, 0, stream>>>(xh, W_ih, W_hh, gates);
    }
    k_fin<<<dim3(NB), 256, 0, stream>>>(gates, hcbuf, hseqB);

    gemm_preds_mfma<<<dim3(2560), 256, 0, stream>>>(hseqB, W_fc, b_fc, out, rowmap, mpad);
}

// Round 13
// 1883.996 us; speedup vs baseline: 1.4649x; 1.4649x over previous
//
#include <hip/hip_runtime.h>
#include <hip/hip_bf16.h>
#include <cstddef>

#define NB 32      // batch
#define NP 196     // pixels
#define NE 2048    // encoder dim
#define ND 512     // decoder/att/emb dim
#define NV 32000   // vocab
#define NL 21
#define NT 20      // decode steps

typedef __attribute__((ext_vector_type(8))) short short8;   // 8 bf16 (4 VGPRs)
typedef __attribute__((ext_vector_type(4))) float f32x4;

__device__ __forceinline__ unsigned short f2b(float f) {
    __hip_bfloat16 h = __float2bfloat16(f);      // RNE
    return *reinterpret_cast<unsigned short*>(&h);
}
__device__ __forceinline__ float b2f_lo(unsigned int u) {
    union { unsigned int i; float f; } v; v.i = u << 16; return v.f;
}
__device__ __forceinline__ float b2f_hi(unsigned int u) {
    union { unsigned int i; float f; } v; v.i = u & 0xffff0000u; return v.f;
}

// ---------------- setup ----------------

__global__ void k_sort(const int* __restrict__ lens, int* __restrict__ sind, int* __restrict__ dlens,
                       int* __restrict__ rowmap, int* __restrict__ mpad)
{
    int i = threadIdx.x;
    if (i < NB) {
        int li = lens[i];
        int r = 0;
        for (int j = 0; j < NB; ++j) {
            int lj = lens[j];
            if (lj > li || (lj == li && j < i)) ++r;
        }
        sind[r] = i;
        dlens[r] = li - 1;
    }
    __syncthreads();
    if (i == 0) {
        int c = 0;
        for (int t = 0; t < NT; ++t)
            for (int b = 0; b < NB; ++b)
                if (t < dlens[b]) rowmap[c++] = t * NB + b;
        int pad = (c + 63) & ~63;
        for (int r = c; r < pad; ++r) rowmap[r] = -1;
        mpad[0] = pad;
    }
}

__global__ __launch_bounds__(256) void k_mean(const float* __restrict__ enc, const int* __restrict__ sind,
                                              float* __restrict__ mean_enc)
{
    int b = blockIdx.y;
    int k = blockIdx.x * 256 + threadIdx.x;
    const float* e = enc + (size_t)sind[b] * NP * NE + k;
    float s0 = 0.f, s1 = 0.f, s2 = 0.f, s3 = 0.f;
    for (int p = 0; p < NP; p += 4) {
        s0 += e[(size_t)(p + 0) * NE];
        s1 += e[(size_t)(p + 1) * NE];
        s2 += e[(size_t)(p + 2) * NE];
        s3 += e[(size_t)(p + 3) * NE];
    }
    mean_enc[(size_t)b * NE + k] = (s0 + s1 + s2 + s3) * (1.0f / NP);
}

__global__ __launch_bounds__(256) void k_zero(const int* __restrict__ dlens, float* __restrict__ out)
{
    int b = blockIdx.x / NT, t = blockIdx.x % NT;
    if (t < dlens[b]) return;
    float4 z = {0.f, 0.f, 0.f, 0.f};
    float4* row = (float4*)(out + ((size_t)b * NT + t) * NV);
    for (int i = threadIdx.x; i < NV / 4; i += 256) row[i] = z;
}

// ---------------- h0/c0 skinny GEMM, split-K=8 (grid 16 x 8) -> partials in spart ----------------
__global__ __launch_bounds__(256) void gemm_skinny_split(
    const float* __restrict__ A0, const float* __restrict__ W0a, const float* __restrict__ W0b,
    float* __restrict__ spart)
{
    __shared__ float As[32][32];
    __shared__ float Ws[64][33];
    int n0 = blockIdx.x * 64;
    int ks = blockIdx.y;
    int tid = threadIdx.x;
    int lb = tid / 8, lkq = tid % 8;
    int b4 = (tid / 32) * 4, nl = (tid % 32) * 2;
    float acc[4][2] = {};
    for (int kt = ks * 256; kt < ks * 256 + 256; kt += 32) {
        float4 a4 = *reinterpret_cast<const float4*>(A0 + (size_t)lb * NE + kt + lkq * 4);
        As[lkq * 4 + 0][lb] = a4.x; As[lkq * 4 + 1][lb] = a4.y;
        As[lkq * 4 + 2][lb] = a4.z; As[lkq * 4 + 3][lb] = a4.w;
        #pragma unroll
        for (int r = 0; r < 2; ++r) {
            int s = tid + r * 256;
            int n_l = s / 8, kq = s % 8;
            int ng = n0 + n_l;
            const float* wrow = (ng < 512) ? (W0a + (size_t)ng * NE)
                                           : (W0b + (size_t)(ng - 512) * NE);
            float4 w4 = *reinterpret_cast<const float4*>(wrow + kt + kq * 4);
            Ws[n_l][kq * 4 + 0] = w4.x; Ws[n_l][kq * 4 + 1] = w4.y;
            Ws[n_l][kq * 4 + 2] = w4.z; Ws[n_l][kq * 4 + 3] = w4.w;
        }
        __syncthreads();
        #pragma unroll
        for (int k = 0; k < 32; ++k) {
            float4 av = *reinterpret_cast<const float4*>(&As[k][b4]);
            float w0 = Ws[nl][k], w1 = Ws[nl + 1][k];
            acc[0][0] += av.x * w0; acc[0][1] += av.x * w1;
            acc[1][0] += av.y * w0; acc[1][1] += av.y * w1;
            acc[2][0] += av.z * w0; acc[2][1] += av.z * w1;
            acc[3][0] += av.w * w0; acc[3][1] += av.w * w1;
        }
        __syncthreads();
    }
    float* Cp = spart + (size_t)ks * NB * 1024;
    #pragma unroll
    for (int j = 0; j < 2; ++j)
        #pragma unroll
        for (int i = 0; i < 4; ++i)
            Cp[(size_t)(b4 + i) * 1024 + n0 + nl + j] = acc[i][j];
}

// combine partials + bias -> hc; seed xh h-part (grid NB)
__global__ __launch_bounds__(256) void k_hc0(
    const float* __restrict__ spart, const float* __restrict__ ba, const float* __restrict__ bb,
    float* __restrict__ hc, float* __restrict__ xh)
{
    int b = blockIdx.x;
    for (int ng = threadIdx.x; ng < 1024; ng += 256) {
        float s = (ng < 512) ? ba[ng] : bb[ng - 512];
        #pragma unroll
        for (int ks = 0; ks < 8; ++ks)
            s += spart[(size_t)ks * NB * 1024 + (size_t)b * 1024 + ng];
        hc[(size_t)b * 1024 + ng] = s;
        if (ng < 512) xh[(size_t)b * 3072 + 2560 + ng] = s;
    }
}

// ---------------- att1 GEMM (bf16 MFMA), XCD-swizzled ----------------
__global__ __launch_bounds__(256) void gemm_att1_mfma(
    const float* __restrict__ enc, const float* __restrict__ W_ea,
    const float* __restrict__ bias, unsigned short* __restrict__ att1B,
    const int* __restrict__ sind)
{
    int fid = blockIdx.x;
    int c = fid & 7, x = (fid >> 3) & 7, pg = fid >> 6;
    int p = pg * 8 + c;
    if (p >= 98) return;
    int bm0 = p * 64, bn0 = x * 64;
    __shared__ unsigned short As[64][40];
    __shared__ unsigned short Bs[64][40];
    int tid = threadIdx.x;
    int w = tid >> 6, lane = tid & 63;
    int srow = tid >> 2, schunk = (tid & 3) * 8;
    int mg = bm0 + srow;
    int bidx = mg / NP, pp = mg - bidx * NP;
    const float* arow = enc + ((size_t)sind[bidx] * NP + pp) * NE + schunk;
    const float* brow = W_ea + (size_t)(bn0 + srow) * NE + schunk;
    int frow = lane & 15, fk = (lane >> 4) * 8;
    f32x4 acc[4] = {};
    for (int kt = 0; kt < NE; kt += 32) {
        float4 a0 = *reinterpret_cast<const float4*>(arow + kt);
        float4 a1 = *reinterpret_cast<const float4*>(arow + kt + 4);
        float4 b0 = *reinterpret_cast<const float4*>(brow + kt);
        float4 b1 = *reinterpret_cast<const float4*>(brow + kt + 4);
        uint4 av, bv;
        av.x = f2b(a0.x) | ((unsigned)f2b(a0.y) << 16);
        av.y = f2b(a0.z) | ((unsigned)f2b(a0.w) << 16);
        av.z = f2b(a1.x) | ((unsigned)f2b(a1.y) << 16);
        av.w = f2b(a1.z) | ((unsigned)f2b(a1.w) << 16);
        bv.x = f2b(b0.x) | ((unsigned)f2b(b0.y) << 16);
        bv.y = f2b(b0.z) | ((unsigned)f2b(b0.w) << 16);
        bv.z = f2b(b1.x) | ((unsigned)f2b(b1.y) << 16);
        bv.w = f2b(b1.z) | ((unsigned)f2b(b1.w) << 16);
        *reinterpret_cast<uint4*>(&As[srow][schunk]) = av;
        *reinterpret_cast<uint4*>(&Bs[srow][schunk]) = bv;
        __syncthreads();
        short8 af = *reinterpret_cast<const short8*>(&As[w * 16 + frow][fk]);
        #pragma unroll
        for (int n = 0; n < 4; ++n) {
            short8 bf = *reinterpret_cast<const short8*>(&Bs[n * 16 + frow][fk]);
            acc[n] = __builtin_amdgcn_mfma_f32_16x16x32_bf16(af, bf, acc[n], 0, 0, 0);
        }
        __syncthreads();
    }
    int crow = bm0 + w * 16 + (lane >> 4) * 4;
    int ccol0 = lane & 15;
    #pragma unroll
    for (int n = 0; n < 4; ++n) {
        int col = bn0 + n * 16 + ccol0;
        float bb2 = bias[col];
        #pragma unroll
        for (int i = 0; i < 4; ++i)
            att1B[(size_t)(crow + i) * ND + col] = f2b(acc[n][i] + bb2);
    }
}

// ---------------- preds GEMM (bf16 MFMA), XCD-swizzled ----------------
__global__ __launch_bounds__(256) void gemm_preds_mfma(
    const unsigned short* __restrict__ hseqB, const float* __restrict__ W_fc,
    const float* __restrict__ bias, float* __restrict__ out,
    const int* __restrict__ rowmap, const int* __restrict__ mpad)
{
    int fid = blockIdx.x;
    int c = fid & 7;
    int rem = fid >> 3;
    int m = rem % 10, g = rem / 10;
    int n = g * 8 + c;
    if (n >= 250) return;
    int bm0 = m * 64;
    if (bm0 >= mpad[0]) return;
    int bn0 = n * 128;
    __shared__ unsigned short As[64][40];
    __shared__ unsigned short Bs[128][40];
    int tid = threadIdx.x;
    int w = tid >> 6, lane = tid & 63;
    int srow = tid >> 2, schunk = (tid & 3) * 8;
    int rid = rowmap[bm0 + srow];
    const unsigned short* aptr = hseqB + (size_t)(rid < 0 ? 0 : rid) * ND + schunk;
    const float* bptr0 = W_fc + (size_t)(bn0 + srow) * ND + schunk;
    const float* bptr1 = W_fc + (size_t)(bn0 + 64 + srow) * ND + schunk;
    int frow = lane & 15, fk = (lane >> 4) * 8;
    f32x4 acc[8] = {};
    for (int kt = 0; kt < ND; kt += 32) {
        uint4 av = *reinterpret_cast<const uint4*>(aptr + kt);
        float4 c0 = *reinterpret_cast<const float4*>(bptr0 + kt);
        float4 c1 = *reinterpret_cast<const float4*>(bptr0 + kt + 4);
        float4 d0 = *reinterpret_cast<const float4*>(bptr1 + kt);
        float4 d1 = *reinterpret_cast<const float4*>(bptr1 + kt + 4);
        uint4 bv0, bv1;
        bv0.x = f2b(c0.x) | ((unsigned)f2b(c0.y) << 16);
        bv0.y = f2b(c0.z) | ((unsigned)f2b(c0.w) << 16);
        bv0.z = f2b(c1.x) | ((unsigned)f2b(c1.y) << 16);
        bv0.w = f2b(c1.z) | ((unsigned)f2b(c1.w) << 16);
        bv1.x = f2b(d0.x) | ((unsigned)f2b(d0.y) << 16);
        bv1.y = f2b(d0.z) | ((unsigned)f2b(d0.w) << 16);
        bv1.z = f2b(d1.x) | ((unsigned)f2b(d1.y) << 16);
        bv1.w = f2b(d1.z) | ((unsigned)f2b(d1.w) << 16);
        *reinterpret_cast<uint4*>(&As[srow][schunk]) = av;
        *reinterpret_cast<uint4*>(&Bs[srow][schunk]) = bv0;
        *reinterpret_cast<uint4*>(&Bs[64 + srow][schunk]) = bv1;
        __syncthreads();
        short8 af = *reinterpret_cast<const short8*>(&As[w * 16 + frow][fk]);
        #pragma unroll
        for (int nn = 0; nn < 8; ++nn) {
            short8 bf = *reinterpret_cast<const short8*>(&Bs[nn * 16 + frow][fk]);
            acc[nn] = __builtin_amdgcn_mfma_f32_16x16x32_bf16(af, bf, acc[nn], 0, 0, 0);
        }
        __syncthreads();
    }
    int rl0 = w * 16 + (lane >> 4) * 4;
    int ccol0 = lane & 15;
    #pragma unroll
    for (int i = 0; i < 4; ++i) {
        int rm = rowmap[bm0 + rl0 + i];
        if (rm < 0) continue;
        int t = rm / NB, b = rm % NB;
        float* orow = out + ((size_t)b * NT + t) * NV;
        #pragma unroll
        for (int nn = 0; nn < 8; ++nn) {
            int col = bn0 + nn * 16 + ccol0;
            orow[col] = acc[nn][i] + bias[col];
        }
    }
}

// ---------------- k_attg: attg[32][2560] = h @ [W_da;W_fb]^T + [b_da;b_fb] (40 blocks) ----------------
__global__ __launch_bounds__(256) void k_attg(
    const float* __restrict__ hc, const float* __restrict__ W_da, const float* __restrict__ W_fb,
    const float* __restrict__ b_da, const float* __restrict__ b_fb, float* __restrict__ attg)
{
    __shared__ float As[32][32];
    __shared__ float Ws[64][33];
    int n0 = blockIdx.x * 64;
    int tid = threadIdx.x;
    int lb = tid / 8, lkq = tid % 8;
    int b4 = (tid / 32) * 4, nl = (tid % 32) * 2;
    float acc[4][2] = {};
    for (int kt = 0; kt < 512; kt += 32) {
        float4 a4 = *reinterpret_cast<const float4*>(hc + (size_t)lb * 1024 + kt + lkq * 4);
        As[lkq * 4 + 0][lb] = a4.x; As[lkq * 4 + 1][lb] = a4.y;
        As[lkq * 4 + 2][lb] = a4.z; As[lkq * 4 + 3][lb] = a4.w;
        #pragma unroll
        for (int r = 0; r < 2; ++r) {
            int s = tid + r * 256;
            int n_l = s / 8, kq = s % 8;
            int ng = n0 + n_l;
            const float* wrow = (ng < 512) ? (W_da + (size_t)ng * 512)
                                           : (W_fb + (size_t)(ng - 512) * 512);
            float4 w4 = *reinterpret_cast<const float4*>(wrow + kt + kq * 4);
            Ws[n_l][kq * 4 + 0] = w4.x; Ws[n_l][kq * 4 + 1] = w4.y;
            Ws[n_l][kq * 4 + 2] = w4.z; Ws[n_l][kq * 4 + 3] = w4.w;
        }
        __syncthreads();
        #pragma unroll
        for (int k = 0; k < 32; ++k) {
            float4 av = *reinterpret_cast<const float4*>(&As[k][b4]);
            float w0 = Ws[nl][k], w1 = Ws[nl + 1][k];
            acc[0][0] += av.x * w0; acc[0][1] += av.x * w1;
            acc[1][0] += av.y * w0; acc[1][1] += av.y * w1;
            acc[2][0] += av.z * w0; acc[2][1] += av.z * w1;
            acc[3][0] += av.w * w0; acc[3][1] += av.w * w1;
        }
        __syncthreads();
    }
    #pragma unroll
    for (int j = 0; j < 2; ++j) {
        int ng = n0 + nl + j;
        float bias = (ng < 512) ? b_da[ng] : b_fb[ng - 512];
        #pragma unroll
        for (int i = 0; i < 4; ++i)
            attg[(size_t)(b4 + i) * 2560 + ng] = acc[i][j] + bias;
    }
}

// ---------------- k_att: e (thread-per-p) + softmax + awe + gate + xh + gates bias-init
//                  (grid 8 x 32) ----------------
__global__ __launch_bounds__(256) void k_att(
    const float* __restrict__ enc, const int* __restrict__ sind, const int* __restrict__ dlens,
    const int* __restrict__ caps, const float* __restrict__ emb_W,
    const unsigned short* __restrict__ att1B, const float* __restrict__ attg,
    const float* __restrict__ w_fa, const float* __restrict__ b_fa,
    const float* __restrict__ b_ih, const float* __restrict__ b_hh,
    float* __restrict__ xh, float* __restrict__ gates,
    float* __restrict__ out_alpha, int t)
{
    __shared__ float att2s[512];
    __shared__ float wfas[512];
    __shared__ float es[256];
    __shared__ float red[256];
    int kc = blockIdx.x, b = blockIdx.y, tid = threadIdx.x;
    const float* ag = attg + (size_t)b * 2560;
    att2s[tid] = ag[tid]; att2s[256 + tid] = ag[256 + tid];
    wfas[tid] = w_fa[tid]; wfas[256 + tid] = w_fa[256 + tid];
    __syncthreads();
    // e score: one thread per p, 512-dim dot on bf16 att1 row
    float ev = -1e30f;
    if (tid < NP) {
        const unsigned short* row = att1B + ((size_t)b * NP + tid) * ND;
        float s0 = 0.f, s1 = 0.f;
        #pragma unroll 8
        for (int d = 0; d < 512; d += 8) {
            uint4 u = *reinterpret_cast<const uint4*>(row + d);
            s0 += fmaxf(b2f_lo(u.x) + att2s[d + 0], 0.f) * wfas[d + 0];
            s1 += fmaxf(b2f_hi(u.x) + att2s[d + 1], 0.f) * wfas[d + 1];
            s0 += fmaxf(b2f_lo(u.y) + att2s[d + 2], 0.f) * wfas[d + 2];
            s1 += fmaxf(b2f_hi(u.y) + att2s[d + 3], 0.f) * wfas[d + 3];
            s0 += fmaxf(b2f_lo(u.z) + att2s[d + 4], 0.f) * wfas[d + 4];
            s1 += fmaxf(b2f_hi(u.z) + att2s[d + 5], 0.f) * wfas[d + 5];
            s0 += fmaxf(b2f_lo(u.w) + att2s[d + 6], 0.f) * wfas[d + 6];
            s1 += fmaxf(b2f_hi(u.w) + att2s[d + 7], 0.f) * wfas[d + 7];
        }
        ev = s0 + s1 + b_fa[0];
    }
    red[tid] = ev; __syncthreads();
    for (int s2 = 128; s2 > 0; s2 >>= 1) { if (tid < s2) red[tid] = fmaxf(red[tid], red[tid + s2]); __syncthreads(); }
    float m = red[0]; __syncthreads();
    float xe = (tid < NP) ? expf(ev - m) : 0.f;
    red[tid] = xe; __syncthreads();
    for (int s2 = 128; s2 > 0; s2 >>= 1) { if (tid < s2) red[tid] += red[tid + s2]; __syncthreads(); }
    float inv = 1.0f / red[0];
    __syncthreads();
    es[tid] = xe * inv;
    __syncthreads();

    // gates bias-init for this (b, kc) slice (consumed by k_gates atomicAdd)
    int n = kc * 256 + tid;
    gates[(size_t)b * 2048 + n] = b_ih[n] + b_hh[n];

    // awe + gate for this block's 256 k-columns
    int k = kc * 256 + tid;
    const float* ec = enc + (size_t)sind[b] * NP * NE + k;
    float s0 = 0.f, s1 = 0.f, s2v = 0.f, s3 = 0.f;
    #pragma unroll 4
    for (int p = 0; p < NP; p += 4) {
        s0 += es[p + 0] * ec[(size_t)(p + 0) * NE];
        s1 += es[p + 1] * ec[(size_t)(p + 1) * NE];
        s2v += es[p + 2] * ec[(size_t)(p + 2) * NE];
        s3 += es[p + 3] * ec[(size_t)(p + 3) * NE];
    }
    float awe = (s0 + s1) + (s2v + s3);
    float gp = ag[512 + k];                     // includes b_fb
    float gate = 1.f / (1.f + expf(-gp));
    xh[(size_t)b * 3072 + 512 + k] = gate * awe;
    if (kc == 0) {
        bool live = (t < dlens[b]);
        if (tid < NP) out_alpha[((size_t)b * NT + t) * NP + tid] = live ? es[tid] : 0.f;
        const float* er = emb_W + (size_t)caps[sind[b] * NL + t] * ND;
        xh[(size_t)b * 3072 + tid] = er[tid];
        xh[(size_t)b * 3072 + 256 + tid] = er[256 + tid];
    }
}

// ---------------- k_gates: gates GEMM, atomicAdd into bias-initialized gates ----------------
__global__ __launch_bounds__(256) void k_gates(
    const float* __restrict__ xh, const float* __restrict__ W_ih, const float* __restrict__ W_hh,
    float* __restrict__ gates)
{
    __shared__ float smem[3200];
    int blk = blockIdx.x, tid = threadIdx.x;
    int nt = blk & 31, ks = blk >> 5;
    float* As = smem;
    float (*Ws)[33] = (float(*)[33])(smem + 1024);
    int n0 = nt * 64;
    int lb = tid / 8, lkq = tid % 8;
    int b4 = (tid / 32) * 4, nl = (tid % 32) * 2;
    float acc[4][2] = {};
    for (int kt = ks * 768; kt < ks * 768 + 768; kt += 32) {
        float4 a4 = *reinterpret_cast<const float4*>(xh + (size_t)lb * 3072 + kt + lkq * 4);
        As[(lkq * 4 + 0) * 32 + lb] = a4.x; As[(lkq * 4 + 1) * 32 + lb] = a4.y;
        As[(lkq * 4 + 2) * 32 + lb] = a4.z; As[(lkq * 4 + 3) * 32 + lb] = a4.w;
        #pragma unroll
        for (int r = 0; r < 2; ++r) {
            int s = tid + r * 256;
            int n_l = s / 8, kq = s % 8;
            int ng = n0 + n_l;
            int kk = kt + kq * 4;
            const float* wrow = (kk < 2560) ? (W_ih + (size_t)ng * 2560 + kk)
                                            : (W_hh + (size_t)ng * 512 + (kk - 2560));
            float4 w4 = *reinterpret_cast<const float4*>(wrow);
            Ws[n_l][kq * 4 + 0] = w4.x; Ws[n_l][kq * 4 + 1] = w4.y;
            Ws[n_l][kq * 4 + 2] = w4.z; Ws[n_l][kq * 4 + 3] = w4.w;
        }
        __syncthreads();
        #pragma unroll
        for (int k = 0; k < 32; ++k) {
            float4 av = *reinterpret_cast<const float4*>(&As[k * 32 + b4]);
            float w0 = Ws[nl][k], w1 = Ws[nl + 1][k];
            acc[0][0] += av.x * w0; acc[0][1] += av.x * w1;
            acc[1][0] += av.y * w0; acc[1][1] += av.y * w1;
            acc[2][0] += av.z * w0; acc[2][1] += av.z * w1;
            acc[3][0] += av.w * w0; acc[3][1] += av.w * w1;
        }
        __syncthreads();
    }
    #pragma unroll
    for (int j = 0; j < 2; ++j)
        #pragma unroll
        for (int i = 0; i < 4; ++i)
            atomicAdd(&gates[(size_t)(b4 + i) * 2048 + n0 + nl + j], acc[i][j]);
}

// ---------------- k_cell: LSTM cell from reduced gates (grid NB); hseq stored bf16 ----------------
__global__ __launch_bounds__(256) void k_cell(
    const float* __restrict__ gates, const int* __restrict__ dlens,
    float* __restrict__ hc, unsigned short* __restrict__ hseqB, float* __restrict__ xh, int t)
{
    int b = blockIdx.x;
    const float* gb = gates + (size_t)b * 2048;
    for (int d = threadIdx.x; d < ND; d += 256) {
        float g0 = gb[d], g1 = gb[512 + d], g2 = gb[1024 + d], g3 = gb[1536 + d];
        float ig = 1.f / (1.f + expf(-g0));
        float fg = 1.f / (1.f + expf(-g1));
        float gt = tanhf(g2);
        float og = 1.f / (1.f + expf(-g3));
        float c_old = hc[(size_t)b * 1024 + 512 + d];
        float c_new = fg * c_old + ig * gt;
        float h_new = og * tanhf(c_new);
        hseqB[((size_t)t * NB + b) * ND + d] = f2b(h_new);
        if (t < dlens[b]) {
            hc[(size_t)b * 1024 + d] = h_new;
            hc[(size_t)b * 1024 + 512 + d] = c_new;
            xh[(size_t)b * 3072 + 2560 + d] = h_new;
        }
    }
}

// ---------------- launcher ----------------
extern "C" void kernel_launch(void* const* d_in, const int* in_sizes, int n_in,
                              void* d_out, int out_size, void* d_ws, size_t ws_size,
                              hipStream_t stream)
{
    const float* enc   = (const float*)d_in[0];
    const int*   caps  = (const int*)d_in[1];
    const int*   clens = (const int*)d_in[2];
    const float* emb_W = (const float*)d_in[3];
    const float* W_ea  = (const float*)d_in[4];
    const float* b_ea  = (const float*)d_in[5];
    const float* W_da  = (const float*)d_in[6];
    const float* b_da  = (const float*)d_in[7];
    const float* w_fa  = (const float*)d_in[8];
    const float* b_fa  = (const float*)d_in[9];
    const float* W_ih  = (const float*)d_in[10];
    const float* b_ih  = (const float*)d_in[11];
    const float* W_hh  = (const float*)d_in[12];
    const float* b_hh  = (const float*)d_in[13];
    const float* W_h0  = (const float*)d_in[14];
    const float* b_h0  = (const float*)d_in[15];
    const float* W_c0  = (const float*)d_in[16];
    const float* b_c0  = (const float*)d_in[17];
    const float* W_fb  = (const float*)d_in[18];
    const float* b_fb  = (const float*)d_in[19];
    const float* W_fc  = (const float*)d_in[20];
    const float* b_fc  = (const float*)d_in[21];

    float* out = (float*)d_out;
    float* out_alpha = out + (size_t)NB * NT * NV;

    int* iws    = (int*)d_ws;
    int* sind   = iws;
    int* dlens  = iws + 32;
    int* rowmap = iws + 64;
    int* mpad   = iws + 704;
    float* base = (float*)d_ws + 1024;
    float* mean_enc = base;                         // 65536
    float* hc    = mean_enc + NB * NE;              // 32768 (h|c per b)
    float* attg  = hc + NB * 1024;                  // 81920
    float* xh    = attg + NB * 2560;                // 98304
    float* gates = xh + NB * 3072;                  // 65536 used; 262144 reserved (spart at setup)
    unsigned short* att1B = (unsigned short*)(gates + 262144);          // 6272*512 bf16
    unsigned short* hseqB = att1B + (size_t)NB * NP * ND;               // 640*512 bf16

    k_sort<<<1, 64, 0, stream>>>(clens, sind, dlens, rowmap, mpad);
    k_zero<<<NB * NT, 256, 0, stream>>>(dlens, out);
    k_mean<<<dim3(NE / 256, NB), 256, 0, stream>>>(enc, sind, mean_enc);
    gemm_skinny_split<<<dim3(16, 8), 256, 0, stream>>>(mean_enc, W_h0, W_c0, gates);
    k_hc0<<<dim3(NB), 256, 0, stream>>>(gates, b_h0, b_c0, hc, xh);
    gemm_att1_mfma<<<dim3(832), 256, 0, stream>>>(enc, W_ea, b_ea, att1B, sind);

    for (int t = 0; t < NT; ++t) {
        k_attg<<<dim3(40), 256, 0, stream>>>(hc, W_da, W_fb, b_da, b_fb, attg);
        k_att<<<dim3(8, NB), 256, 0, stream>>>(enc, sind, dlens, caps, emb_W,
                                               att1B, attg, w_fa, b_fa, b_ih, b_hh,
                                               xh, gates, out_alpha, t);
        k_gates<<<dim3(128), 256, 0, stream>>>(xh, W_ih, W_hh, gates);
        k_cell<<<dim3(NB), 256, 0, stream>>>(gates, dlens, hc, hseqB, xh, t);
    }

    gemm_preds_mfma<<<dim3(2560), 256, 0, stream>>>(hseqB, W_fc, b_fc, out, rowmap, mpad);
}